// Round 6
// baseline (544.197 us; speedup 1.0000x reference)
//
#include <hip/hip_runtime.h>
#include <hip/hip_bf16.h>

#define LFULL 8192
#define HDIM 1024
#define KPAD 8448  // 66 chunks of 128 elems (last 2 chunks zeros)

typedef __attribute__((ext_vector_type(8))) short bf16x8;
typedef __attribute__((ext_vector_type(4))) float f32x4;
typedef __attribute__((ext_vector_type(16))) float f32x16;

union U16 {
  uint4 u;
  bf16x8 s;
  ushort e[8];
};

__device__ __forceinline__ ushort f2bf(float x) {
  union { float f; uint u; } a;
  a.f = x;
  uint r = a.u + 0x7fffu + ((a.u >> 16) & 1u);
  return (ushort)(r >> 16);
}
__device__ __forceinline__ float bf2f(ushort x) {
  union { uint u; float f; } a;
  a.u = ((uint)x) << 16;
  return a.f;
}

__device__ __forceinline__ void gload16(const void* src, void* lds) {
  __builtin_amdgcn_global_load_lds(
      (const __attribute__((address_space(1))) unsigned int*)src,
      (__attribute__((address_space(3))) unsigned int*)lds, 16, 0, 0);
}

__device__ __forceinline__ uint ALIGNB(uint hi, uint lo, uint sh) {
#if __has_builtin(__builtin_amdgcn_alignbyte)
  return __builtin_amdgcn_alignbyte(hi, lo, sh);
#else
  return (uint)((((unsigned long long)hi << 32) | (unsigned long long)lo) >> (8u * sh));
#endif
}

// 4-bit XOR swizzle for Us 16B-chunk index (bijective: low4 ^= bits7:4)
#define USWZ16(cI) ((cI) ^ (((cI) >> 4) & 15))

// ---------------------------------------------------------------------------
// Kernel 1: multi-scale kernel synthesis + L2 norm -> bf16 kbrev[h][8448]
// kbrev[h][x] = k_norm[h][8191-x], zeros for x >= 8192.
// ---------------------------------------------------------------------------
__global__ __launch_bounds__(256) void k_synth_kernel(
    const float* __restrict__ kern, ushort* __restrict__ kout) {
  const int h = blockIdx.x;
  const int tid = threadIdx.x;
  __shared__ float Kw[8][64];
  __shared__ __align__(16) float kv[LFULL];
  __shared__ float red[8];
  for (int idx = tid; idx < 8 * 64; idx += 256) {
    int i = idx >> 6, j = idx & 63;
    Kw[i][j] = kern[(i * HDIM + h) * 64 + j];
  }
  __syncthreads();
  const float mult = (float)(1.0 + 3.0 * (double)h / 1023.0);
  float pw[8];
  pw[7] = 1.0f;
#pragma unroll
  for (int i = 6; i >= 0; --i) pw[i] = pw[i + 1] * mult;
  float ss = 0.0f;
  for (int m = tid; m < LFULL; m += 256) {
    const int i = (m < 64) ? 0 : (32 - __clz(m >> 6));
    const int slog = (i == 0) ? 0 : (i - 1);
    const float inv_s = 1.0f / (float)(1 << slog);
    const int off = (i == 0) ? 0 : (64 << (i - 1));
    const int t = m - off;
    const float pos = ((float)t + 0.5f) * inv_s - 0.5f;
    const float lof = floorf(pos);
    const float wgt = pos - lof;
    int lo = (int)lof;
    int hi = lo + 1;
    lo = min(63, max(0, lo));
    hi = min(63, max(0, hi));
    const float val = (Kw[i][lo] * (1.0f - wgt) + Kw[i][hi] * wgt) * pw[i];
    kv[m] = val;
    ss += val * val;
  }
#pragma unroll
  for (int o = 32; o > 0; o >>= 1) ss += __shfl_xor(ss, o, 64);
  if ((tid & 63) == 0) red[tid >> 6] = ss;
  __syncthreads();
  if (tid == 0) red[0] = sqrtf(red[0] + red[1] + red[2] + red[3]);
  __syncthreads();
  const float inv_norm = 1.0f / red[0];
  ushort* krow = kout + (size_t)h * KPAD;
  for (int m = tid; m < LFULL; m += 256) krow[8191 - m] = f2bf(kv[m] * inv_norm);
  if (tid < 256) krow[8192 + tid] = 0;
}

// ---------------------------------------------------------------------------
// Kernel 2: causal conv via block-Toeplitz 32x32x16 MFMA, T=128 blocks.
// Grid 2048 = (h, b-pair). Block: 4 waves = (b-local bl, col-half ch).
// Per wave: acc = 2 F x 2 rg (64 AGPR). A-windows built JIT into a 4-slot
// rolling cache (static reg indexing), no cross-step carry. kbrev streamed
// through per-wave 8-slot LDS rings (reg-staged). No barriers in main loop.
// 3 waves/SIMD target (LDS 41 KB/block -> 3 blocks/CU).
// ---------------------------------------------------------------------------
__global__ __launch_bounds__(256, 3) void conv_mfma_kernel(
    const float* __restrict__ u, const ushort* __restrict__ kbrev,
    const float* __restrict__ Dp, ushort* __restrict__ g) {
  __shared__ __align__(16) ushort Us[2 * LFULL];   // 32 KB (2 b-rows)
  __shared__ __align__(16) ushort Ring[4][1152];   // 9 KB: 8 slots + dup
  const int tid = threadIdx.x;
  const int h = blockIdx.x >> 1;
  const int bp = blockIdx.x & 1;
  const int w = tid >> 6;
  const int bl = w >> 1;   // b-local
  const int ch = w & 1;    // col-half
  const int b = bp * 2 + bl;
  const int lane = tid & 63;
  const int c32 = lane & 31;
  const int qh = lane >> 5;
  uint4* Us4 = (uint4*)Us;

  // ---- stage u: fp32 -> bf16, XOR16-swizzled 16B chunks (2 rows) ----
  for (int cc = tid; cc < 2048; cc += 256) {
    const int row = cc >> 10, cI = cc & 1023;
    const float* up =
        u + (((size_t)((bp * 2 + row) * HDIM + h)) << 13) + (cI << 3);
    const float4 v0 = *(const float4*)up;
    const float4 v1 = *(const float4*)(up + 4);
    U16 pk;
    pk.e[0] = f2bf(v0.x); pk.e[1] = f2bf(v0.y);
    pk.e[2] = f2bf(v0.z); pk.e[3] = f2bf(v0.w);
    pk.e[4] = f2bf(v1.x); pk.e[5] = f2bf(v1.y);
    pk.e[6] = f2bf(v1.z); pk.e[7] = f2bf(v1.w);
    Us4[(row << 10) + USWZ16(cI)] = pk.u;
  }

  // ---- ring prologue: chunks 65,64(+dup),63 staged via regs; 62 in kreg ----
  const ushort* kr = kbrev + (size_t)h * KPAD;
  char* ringb = (char*)Ring[w];
  {
    const uint kc65 = *(const uint*)(kr + 65 * 128 + 2 * lane);
    const uint kc64 = *(const uint*)(kr + 64 * 128 + 2 * lane);
    const uint kc63 = *(const uint*)(kr + 63 * 128 + 2 * lane);
    *(uint*)(ringb + 1 * 256 + 4 * lane) = kc65;
    *(uint*)(ringb + 0 * 256 + 4 * lane) = kc64;
    *(uint*)(ringb + 2048 + 4 * lane) = kc64;  // dup of slot 0
    *(uint*)(ringb + 7 * 256 + 4 * lane) = kc63;
  }
  uint kreg = *(const uint*)(kr + 62 * 128 + 2 * lane);
  __syncthreads();

  f32x16 acc[2][2];
#pragma unroll
  for (int f = 0; f < 2; ++f)
#pragma unroll
    for (int rg = 0; rg < 2; ++rg)
#pragma unroll
      for (int q = 0; q < 16; ++q) acc[f][rg][q] = 0.0f;

  const int PBASE = 8191 - c32 + 8 * qh;
  const bool s8 = ((PBASE >> 1) & 1) != 0;
  const uint sh = 2u * (uint)(PBASE & 1);
  int Pstep = PBASE - 64 * ch + 128;  // P0(ks) = Pstep - 128 + 16 ks

  uint4 W4[4];

#define BW_P(PV, DST) {                                                 \
    const int LL = (2 * ((PV) & 1023)) & ~7;                            \
    const uint2 r0 = *(const uint2*)(ringb + LL);                       \
    const uint2 r1 = *(const uint2*)(ringb + LL + 8);                   \
    const uint2 r2 = *(const uint2*)(ringb + LL + 16);                  \
    const uint v0 = s8 ? r0.y : r0.x;                                   \
    const uint v1 = s8 ? r1.x : r0.y;                                   \
    const uint v2 = s8 ? r1.y : r1.x;                                   \
    const uint v3 = s8 ? r2.x : r1.y;                                   \
    const uint v4 = s8 ? r2.y : r2.x;                                   \
    (DST).x = ALIGNB(v1, v0, sh);                                       \
    (DST).y = ALIGNB(v2, v1, sh);                                       \
    (DST).z = ALIGNB(v3, v2, sh);                                       \
    (DST).w = ALIGNB(v4, v3, sh); }

#define RING_MAINT(DD) {                                                \
    const int cw0 = 62 - (DD);                                          \
    const int cw = cw0 < 0 ? 0 : cw0;                                   \
    const int sl = (cw & 7) * 256;                                      \
    *(uint*)(ringb + sl + 4 * lane) = kreg;                             \
    *(uint*)(ringb + ((sl == 0) ? 2048 : sl) + 4 * lane) = kreg;        \
    const int cn0 = 61 - (DD);                                          \
    const int cn = cn0 < 0 ? 0 : cn0;                                   \
    kreg = *(const uint*)(kr + cn * 128 + 2 * lane); }

  // ---- first half: d = 0..31, F=0 (diag-masked) and F=1 (full) ----
  for (int d = 0; d < 32; ++d) {
    RING_MAINT(d);
    const int j00 = c32 - d;
    const int jc0 = j00 < 0 ? 0 : j00;
    const uint mz0 = (j00 < 0) ? 0u : 0xffffffffu;
    const int pb0 = jc0 << 4, px0 = jc0 & 15;
    const int jc1 = 32 + c32 - d;  // always >= 1 here
    const int pb1 = jc1 << 4, px1 = jc1 & 15;
#pragma unroll
    for (int ks = 0; ks < 8; ++ks) {
      const int P0 = Pstep - 128 + 16 * ks;
      BW_P(P0, W4[ks & 3]);
      if (ks < 2) BW_P(P0 - 32, W4[(ks + 2) & 3]);
      const int t = 2 * ks + qh;
      U16 b1;
      b1.u = Us4[(bl << 10) + pb1 + (t ^ px1)];
      acc[1][0] = __builtin_amdgcn_mfma_f32_32x32x16_bf16(
          ((U16*)&W4[ks & 3])->s, b1.s, acc[1][0], 0, 0, 0);
      acc[1][1] = __builtin_amdgcn_mfma_f32_32x32x16_bf16(
          ((U16*)&W4[(ks + 2) & 3])->s, b1.s, acc[1][1], 0, 0, 0);
      U16 b0;
      b0.u = Us4[(bl << 10) + pb0 + (t ^ px0)];
      b0.u.x &= mz0; b0.u.y &= mz0; b0.u.z &= mz0; b0.u.w &= mz0;
      acc[0][0] = __builtin_amdgcn_mfma_f32_32x32x16_bf16(
          ((U16*)&W4[ks & 3])->s, b0.s, acc[0][0], 0, 0, 0);
      acc[0][1] = __builtin_amdgcn_mfma_f32_32x32x16_bf16(
          ((U16*)&W4[(ks + 2) & 3])->s, b0.s, acc[0][1], 0, 0, 0);
    }
    Pstep -= 128;
  }
  // ---- second half: d = 32..63, F=1 only (diag-masked) ----
  for (int d = 32; d < 64; ++d) {
    RING_MAINT(d);
    const int j01 = 32 + c32 - d;
    const int jc1 = j01 < 0 ? 0 : j01;
    const uint mz1 = (j01 < 0) ? 0u : 0xffffffffu;
    const int pb1 = jc1 << 4, px1 = jc1 & 15;
#pragma unroll
    for (int ks = 0; ks < 8; ++ks) {
      const int P0 = Pstep - 128 + 16 * ks;
      BW_P(P0, W4[ks & 3]);
      if (ks < 2) BW_P(P0 - 32, W4[(ks + 2) & 3]);
      const int t = 2 * ks + qh;
      U16 b1;
      b1.u = Us4[(bl << 10) + pb1 + (t ^ px1)];
      b1.u.x &= mz1; b1.u.y &= mz1; b1.u.z &= mz1; b1.u.w &= mz1;
      acc[1][0] = __builtin_amdgcn_mfma_f32_32x32x16_bf16(
          ((U16*)&W4[ks & 3])->s, b1.s, acc[1][0], 0, 0, 0);
      acc[1][1] = __builtin_amdgcn_mfma_f32_32x32x16_bf16(
          ((U16*)&W4[(ks + 2) & 3])->s, b1.s, acc[1][1], 0, 0, 0);
    }
    Pstep -= 128;
  }

  // ---- epilogue: += D*u, exact GELU, bf16 store ----
  const float Dh = Dp[h];
  ushort* gp = g + (((size_t)(b * HDIM + h)) << 13);
#pragma unroll
  for (int f = 0; f < 2; ++f) {
#pragma unroll
    for (int rgl = 0; rgl < 2; ++rgl) {
      const int rg = 2 * ch + rgl;
      const int lbase = (f * 32 + c32) * 128 + rg * 32 + 4 * qh;
#pragma unroll
      for (int rq = 0; rq < 4; ++rq) {
        const int l = lbase + 8 * rq;
        const int cI = l >> 3;
        const int phys = USWZ16(cI);
        const uint2 uv =
            *(const uint2*)(Us + (bl << 13) + (phys << 3) + 4 * qh);
        float uu[4];
        uu[0] = bf2f((ushort)(uv.x & 0xffff));
        uu[1] = bf2f((ushort)(uv.x >> 16));
        uu[2] = bf2f((ushort)(uv.y & 0xffff));
        uu[3] = bf2f((ushort)(uv.y >> 16));
        ushort o[4];
#pragma unroll
        for (int jj = 0; jj < 4; ++jj) {
          const float y = acc[f][rgl][rq * 4 + jj] + Dh * uu[jj];
          const float ge = 0.5f * y * (1.0f + erff(y * 0.70710678118654752f));
          o[jj] = f2bf(ge);
        }
        uint2 op;
        op.x = (uint)o[0] | ((uint)o[1] << 16);
        op.y = (uint)o[2] | ((uint)o[3] << 16);
        *(uint2*)(gp + l) = op;
      }
    }
  }
}

// ---------------------------------------------------------------------------
// Kernel 3: transpose g[b][h][l] -> gt[b][l][h] (64x64 tiles, XOR-swizzled)
// ---------------------------------------------------------------------------
__global__ __launch_bounds__(256) void transpose_kernel(
    const ushort* __restrict__ g, ushort* __restrict__ gt) {
  __shared__ __align__(16) ushort Ts[64 * 64];
  const int l0 = blockIdx.x * 64, hh0 = blockIdx.y * 64, b = blockIdx.z;
  const int tid = threadIdx.x;
#pragma unroll
  for (int p = 0; p < 2; ++p) {
    const int hh = (tid >> 3) + 32 * p;
    const int c8 = tid & 7;
    const uint4 v = *(const uint4*)(g + (((size_t)(b * HDIM + hh0 + hh)) << 13)
                                    + l0 + c8 * 8);
    ((uint4*)Ts)[hh * 8 + (c8 ^ ((hh >> 3) & 7))] = v;
  }
  __syncthreads();
#pragma unroll
  for (int p = 0; p < 2; ++p) {
    const int lr = (tid >> 3) + 32 * p;
    const int o8 = tid & 7;
    U16 pk;
#pragma unroll
    for (int j = 0; j < 8; ++j) {
      const int hq = o8 * 8 + j;
      pk.e[j] = Ts[hq * 64 + (((lr >> 3) ^ o8) << 3) + (lr & 7)];
    }
    ((uint4*)(gt + ((size_t)b * LFULL + l0 + lr) * HDIM + hh0))[o8] = pk.u;
  }
}

// ---------------------------------------------------------------------------
// Kernel 4: W fp32 -> bf16
// ---------------------------------------------------------------------------
__global__ __launch_bounds__(256) void wcvt_kernel(const float* __restrict__ W,
                                                   ushort* __restrict__ Wb) {
  const int i = (blockIdx.x * 256 + threadIdx.x) * 8;
  const float4 v0 = *(const float4*)(W + i);
  const float4 v1 = *(const float4*)(W + i + 4);
  U16 pk;
  pk.e[0] = f2bf(v0.x); pk.e[1] = f2bf(v0.y);
  pk.e[2] = f2bf(v0.z); pk.e[3] = f2bf(v0.w);
  pk.e[4] = f2bf(v1.x); pk.e[5] = f2bf(v1.y);
  pk.e[6] = f2bf(v1.z); pk.e[7] = f2bf(v1.w);
  ((uint4*)Wb)[i >> 3] = pk.u;
}

// ---------------------------------------------------------------------------
// Kernel 5: out[b,o,l] = bo[o] + sum_h Wb[o,h]*gt[b,l,h]  (128x128 MFMA GEMM)
// ---------------------------------------------------------------------------
__global__ __launch_bounds__(256, 2) void outmm_kernel(
    const ushort* __restrict__ Wb, const ushort* __restrict__ gt,
    const float* __restrict__ bo, float* __restrict__ out) {
  __shared__ __align__(16) ushort As[128 * 32];
  __shared__ __align__(16) ushort Bs[128 * 32];
  const int tid = threadIdx.x;
  const int l0 = blockIdx.x * 128, o0 = blockIdx.y * 128, b = blockIdx.z;
  const int w = tid >> 6, lane = tid & 63;
  const int wm = w >> 1, wn = w & 1;
  const int col = lane & 15, q = lane >> 4;
  const int srow = lane >> 2, scol = (lane & 3) * 8;
  f32x4 acc[4][4];
#pragma unroll
  for (int m = 0; m < 4; ++m)
#pragma unroll
    for (int n = 0; n < 4; ++n) acc[m][n] = (f32x4){0.f, 0.f, 0.f, 0.f};
  const ushort* gb = gt + ((size_t)b * LFULL) * HDIM;
  for (int kt = 0; kt < 32; ++kt) {
    const int k0 = kt * 32;
    const int r0 = w * 32;
#pragma unroll
    for (int ii = 0; ii < 2; ++ii) {
      const int ra = r0 + ii * 16 + srow;
      gload16(Wb + (size_t)(o0 + ra) * HDIM + k0 + scol,
              As + (r0 + ii * 16) * 32);
      gload16(gb + (size_t)(l0 + ra) * HDIM + k0 + scol,
              Bs + (r0 + ii * 16) * 32);
    }
    __syncthreads();
    bf16x8 aa[4], bb[4];
#pragma unroll
    for (int m = 0; m < 4; ++m) {
      aa[m] = ((const bf16x8*)As)[(wm * 64 + m * 16 + col) * 4 + q];
      bb[m] = ((const bf16x8*)Bs)[(wn * 64 + m * 16 + col) * 4 + q];
    }
#pragma unroll
    for (int m = 0; m < 4; ++m)
#pragma unroll
      for (int n = 0; n < 4; ++n)
        acc[m][n] = __builtin_amdgcn_mfma_f32_16x16x32_bf16(aa[m], bb[n],
                                                            acc[m][n], 0, 0, 0);
    __syncthreads();
  }
#pragma unroll
  for (int m = 0; m < 4; ++m) {
    const int ob = o0 + wm * 64 + m * 16 + q * 4;
    const float4 bv = *(const float4*)(bo + ob);
    const float bva[4] = {bv.x, bv.y, bv.z, bv.w};
#pragma unroll
    for (int n = 0; n < 4; ++n) {
      const int l = l0 + wn * 64 + n * 16 + col;
      float* op = out + (((size_t)(b * HDIM + ob)) << 13) + l;
#pragma unroll
      for (int v = 0; v < 4; ++v) op[(size_t)v << 13] = acc[m][n][v] + bva[v];
    }
  }
}

// ---------------------------------------------------------------------------
extern "C" void kernel_launch(void* const* d_in, const int* in_sizes, int n_in,
                              void* d_out, int out_size, void* d_ws,
                              size_t ws_size, hipStream_t stream) {
  const float* u = (const float*)d_in[0];     // (4, 1024, 8192)
  const float* kern = (const float*)d_in[1];  // (8, 1, 1024, 64)
  const float* D = (const float*)d_in[2];     // (1, 1024)
  const float* W = (const float*)d_in[3];     // (1024, 1024)
  const float* bo = (const float*)d_in[4];    // (1024,)
  float* out = (float*)d_out;                 // (4, 1024, 8192)

  char* ws = (char*)d_ws;
  ushort* g = (ushort*)ws;                                 // [0, 64 MiB)
  ushort* gt = (ushort*)(ws + ((size_t)64 << 20));         // [64, 128 MiB)
  ushort* kbrev = (ushort*)(ws + ((size_t)128 << 20));     // 1024*8448*2 = 16.5 MiB
  ushort* Wb = (ushort*)(ws + ((size_t)128 << 20));        // reuses kbrev region

  k_synth_kernel<<<HDIM, 256, 0, stream>>>(kern, kbrev);
  conv_mfma_kernel<<<2 * HDIM, 256, 0, stream>>>(u, kbrev, D, g);
  // kbrev dead from here; Wb overlays it.
  wcvt_kernel<<<512, 256, 0, stream>>>(W, Wb);
  transpose_kernel<<<dim3(128, 16, 4), 256, 0, stream>>>(g, gt);
  outmm_kernel<<<dim3(64, 8, 4), 256, 0, stream>>>(Wb, gt, bo, out);
}

// Round 7
// 472.352 us; speedup vs baseline: 1.1521x; 1.1521x over previous
//
#include <hip/hip_runtime.h>
#include <hip/hip_bf16.h>

#define LFULL 8192
#define HDIM 1024
#define KPAD 8448  // 66 chunks of 128 elems (last 2 chunks zeros)

typedef __attribute__((ext_vector_type(8))) short bf16x8;
typedef __attribute__((ext_vector_type(4))) float f32x4;
typedef __attribute__((ext_vector_type(16))) float f32x16;

union U16 {
  uint4 u;
  bf16x8 s;
  ushort e[8];
};

__device__ __forceinline__ ushort f2bf(float x) {
  union { float f; uint u; } a;
  a.f = x;
  uint r = a.u + 0x7fffu + ((a.u >> 16) & 1u);
  return (ushort)(r >> 16);
}
__device__ __forceinline__ float bf2f(ushort x) {
  union { uint u; float f; } a;
  a.u = ((uint)x) << 16;
  return a.f;
}

__device__ __forceinline__ void gload16(const void* src, void* lds) {
  __builtin_amdgcn_global_load_lds(
      (const __attribute__((address_space(1))) unsigned int*)src,
      (__attribute__((address_space(3))) unsigned int*)lds, 16, 0, 0);
}

__device__ __forceinline__ uint ALIGNB(uint hi, uint lo, uint sh) {
#if __has_builtin(__builtin_amdgcn_alignbyte)
  return __builtin_amdgcn_alignbyte(hi, lo, sh);
#else
  return (uint)((((unsigned long long)hi << 32) | (unsigned long long)lo) >> (8u * sh));
#endif
}

// 4-bit XOR swizzle for Us 16B-chunk index (bijective: low4 ^= bits7:4)
#define USWZ16(cI) ((cI) ^ (((cI) >> 4) & 15))

// ---------------------------------------------------------------------------
// Kernel 1: multi-scale kernel synthesis + L2 norm -> bf16 kbrev[h][8448]
// kbrev[h][x] = k_norm[h][8191-x], zeros for x >= 8192.
// ---------------------------------------------------------------------------
__global__ __launch_bounds__(256) void k_synth_kernel(
    const float* __restrict__ kern, ushort* __restrict__ kout) {
  const int h = blockIdx.x;
  const int tid = threadIdx.x;
  __shared__ float Kw[8][64];
  __shared__ __align__(16) float kv[LFULL];
  __shared__ float red[8];
  for (int idx = tid; idx < 8 * 64; idx += 256) {
    int i = idx >> 6, j = idx & 63;
    Kw[i][j] = kern[(i * HDIM + h) * 64 + j];
  }
  __syncthreads();
  const float mult = (float)(1.0 + 3.0 * (double)h / 1023.0);
  float pw[8];
  pw[7] = 1.0f;
#pragma unroll
  for (int i = 6; i >= 0; --i) pw[i] = pw[i + 1] * mult;
  float ss = 0.0f;
  for (int m = tid; m < LFULL; m += 256) {
    const int i = (m < 64) ? 0 : (32 - __clz(m >> 6));
    const int slog = (i == 0) ? 0 : (i - 1);
    const float inv_s = 1.0f / (float)(1 << slog);
    const int off = (i == 0) ? 0 : (64 << (i - 1));
    const int t = m - off;
    const float pos = ((float)t + 0.5f) * inv_s - 0.5f;
    const float lof = floorf(pos);
    const float wgt = pos - lof;
    int lo = (int)lof;
    int hi = lo + 1;
    lo = min(63, max(0, lo));
    hi = min(63, max(0, hi));
    const float val = (Kw[i][lo] * (1.0f - wgt) + Kw[i][hi] * wgt) * pw[i];
    kv[m] = val;
    ss += val * val;
  }
#pragma unroll
  for (int o = 32; o > 0; o >>= 1) ss += __shfl_xor(ss, o, 64);
  if ((tid & 63) == 0) red[tid >> 6] = ss;
  __syncthreads();
  if (tid == 0) red[0] = sqrtf(red[0] + red[1] + red[2] + red[3]);
  __syncthreads();
  const float inv_norm = 1.0f / red[0];
  ushort* krow = kout + (size_t)h * KPAD;
  for (int m = tid; m < LFULL; m += 256) krow[8191 - m] = f2bf(kv[m] * inv_norm);
  if (tid < 256) krow[8192 + tid] = 0;
}

// ---------------------------------------------------------------------------
// Kernel 2: causal conv via block-Toeplitz 32x32x16 MFMA, T=128 blocks.
// Grid 1024 (1 h). Block: 4 waves (wave = b). acc = 2 F x 4 rg (128 AGPR).
// A-windows: kbrev streamed through a SHARED 8-phase-copy LDS ring (copy c
// holds element x at byte 2(x+c) mod 1024). Lane's phase s=(c32+1)&7 is
// constant -> each window is ONE aligned ds_read_b128 (no alignbyte/select).
// Wave w maintains copies 2w,2w+1 (2 ds_write_b32/step, reg-staged from
// global). One lgkmcnt(0)+s_barrier per step (writes are 2 steps ahead of
// reads). 6 windows carried in regs across steps: W(d+1)[m]=W(d)[m+8].
// ---------------------------------------------------------------------------
__global__ __launch_bounds__(256, 2) void conv_mfma_kernel(
    const float* __restrict__ u, const ushort* __restrict__ kbrev,
    const float* __restrict__ Dp, ushort* __restrict__ g) {
  __shared__ __align__(16) ushort Us[4 * LFULL];    // 64 KB
  __shared__ __align__(16) ushort RingC[8 * 512];   // 8 KB: 8 phase copies
  const int tid = threadIdx.x;
  const int h = blockIdx.x;
  const int w = tid >> 6;  // wave index == b
  const int lane = tid & 63;
  const int c32 = lane & 31;
  const int qh = lane >> 5;
  uint4* Us4 = (uint4*)Us;
  char* ringB = (char*)RingC;

  // ---- stage u: fp32 -> bf16, XOR16-swizzled 16B chunks (4 rows) ----
  for (int cc = tid; cc < 4096; cc += 256) {
    const int row = cc >> 10, cI = cc & 1023;
    const float* up = u + (((size_t)(row * HDIM + h)) << 13) + (cI << 3);
    const float4 v0 = *(const float4*)up;
    const float4 v1 = *(const float4*)(up + 4);
    U16 pk;
    pk.e[0] = f2bf(v0.x); pk.e[1] = f2bf(v0.y);
    pk.e[2] = f2bf(v0.z); pk.e[3] = f2bf(v0.w);
    pk.e[4] = f2bf(v1.x); pk.e[5] = f2bf(v1.y);
    pk.e[6] = f2bf(v1.z); pk.e[7] = f2bf(v1.w);
    Us4[(row << 10) + USWZ16(cI)] = pk.u;
  }

  // ---- ring prologue: preload chunks 62,63,64 into copies 2w, 2w+1 ----
  const ushort* kr = kbrev + (size_t)h * KPAD;
  char* ringE = ringB + (2 * w) * 1024;
  char* ringO = ringB + (2 * w + 1) * 1024;
#pragma unroll
  for (int cn = 62; cn <= 64; ++cn) {
    const int x0 = 128 * cn + 2 * lane;
    const uint kEp = *(const uint*)(kr + x0);
    const uint kMp = *(const uint*)(kr + x0 - 2);
    const int off = (2 * x0 + 4 * w) & 1023;
    *(uint*)(ringE + off) = kEp;
    *(uint*)(ringO + off) = ALIGNB(kEp, kMp, 2);
  }
  // prefetch chunk 61 (written at step 0)
  uint kE = *(const uint*)(kr + 61 * 128 + 2 * lane);
  uint kM = *(const uint*)(kr + 61 * 128 + 2 * lane - 2);
  __syncthreads();

  f32x16 acc[2][4];
#pragma unroll
  for (int f = 0; f < 2; ++f)
#pragma unroll
    for (int rg = 0; rg < 4; ++rg)
#pragma unroll
      for (int q = 0; q < 16; ++q) acc[f][rg][q] = 0.0f;

  const int PBASE = 8191 - c32 + 8 * qh;
  const int sph = (c32 + 1) & 7;            // lane's phase copy
  const char* ringR = ringB + sph * 1024;
  int bd = 2 * (PBASE + sph) + 256;         // off(d,mm) = (bd - 32mm) & 1023

  uint4 WF[8];   // fresh windows mm=7..14
  uint4 WC[6];   // carried windows mm=1..6 (zero at d=0: elements >= 8192)
#pragma unroll
  for (int i = 0; i < 6; ++i) WC[i] = make_uint4(0, 0, 0, 0);

#define WGETX(MM) ((MM) >= 7 ? WF[(MM)-7] : WC[(MM)-1])

#define FPART(DD, F, DIAG) {                                            \
    const int j0 = (F) * 32 + c32 - (DD);                               \
    const int jc = j0 < 0 ? 0 : j0;                                     \
    const uint zmask = ((DIAG) && (j0 < 0)) ? 0u : 0xffffffffu;         \
    const int pb = jc << 4;                                             \
    const int px = jc & 15;                                             \
    _Pragma("unroll")                                                   \
    for (int ks = 0; ks < 8; ++ks) {                                    \
      const int t = 2 * ks + qh;                                        \
      U16 bb;                                                           \
      bb.u = Us4[(w << 10) + pb + (t ^ px)];                            \
      if (DIAG) {                                                       \
        bb.u.x &= zmask; bb.u.y &= zmask;                               \
        bb.u.z &= zmask; bb.u.w &= zmask;                               \
      }                                                                 \
      U16 a0, a1, a2, a3;                                               \
      a0.u = WGETX(8 - ks);  a1.u = WGETX(10 - ks);                     \
      a2.u = WGETX(12 - ks); a3.u = WGETX(14 - ks);                     \
      acc[F][0] = __builtin_amdgcn_mfma_f32_32x32x16_bf16(a0.s, bb.s, acc[F][0], 0, 0, 0); \
      acc[F][1] = __builtin_amdgcn_mfma_f32_32x32x16_bf16(a1.s, bb.s, acc[F][1], 0, 0, 0); \
      acc[F][2] = __builtin_amdgcn_mfma_f32_32x32x16_bf16(a2.s, bb.s, acc[F][2], 0, 0, 0); \
      acc[F][3] = __builtin_amdgcn_mfma_f32_32x32x16_bf16(a3.s, bb.s, acc[F][3], 0, 0, 0); \
    } }

#define STEP(DD, HASF0) {                                               \
    const int cw = (61 - (DD)) < 0 ? 0 : (61 - (DD));                   \
    const int offw = (((cw & 3) << 8) + 4 * lane + 4 * w) & 1023;       \
    *(uint*)(ringE + offw) = kE;                                        \
    *(uint*)(ringO + offw) = ALIGNB(kE, kM, 2);                         \
    const int cn = (60 - (DD)) < 0 ? 0 : (60 - (DD));                   \
    const uint kE2 = *(const uint*)(kr + cn * 128 + 2 * lane);          \
    const uint kM2 = *(const uint*)(kr + cn * 128 + 2 * lane - 2);      \
    _Pragma("unroll")                                                   \
    for (int i = 0; i < 8; ++i) {                                       \
      const int off = (bd - 224 - 32 * i) & 1023;                       \
      WF[i] = *(const uint4*)(ringR + off);                             \
    }                                                                   \
    if (HASF0) { FPART(DD, 0, true); FPART(DD, 1, false); }             \
    else { FPART(DD, 1, true); }                                        \
    WC[0] = WF[2]; WC[1] = WF[3]; WC[2] = WF[4];                        \
    WC[3] = WF[5]; WC[4] = WF[6]; WC[5] = WF[7];                        \
    kE = kE2; kM = kM2;                                                 \
    bd -= 256;                                                          \
    asm volatile("s_waitcnt lgkmcnt(0)" ::: "memory");                  \
    __builtin_amdgcn_s_barrier();                                       \
    __builtin_amdgcn_sched_barrier(0);                                  \
  }

  for (int d = 0; d < 32; ++d) { STEP(d, true); }
  for (int d = 32; d < 64; ++d) { STEP(d, false); }

  // ---- epilogue: += D*u, exact GELU, bf16 store ----
  const float Dh = Dp[h];
  ushort* gp = g + (((size_t)(w * HDIM + h)) << 13);
#pragma unroll
  for (int f = 0; f < 2; ++f) {
#pragma unroll
    for (int rg = 0; rg < 4; ++rg) {
      const int lbase = (f * 32 + c32) * 128 + rg * 32 + 4 * qh;
#pragma unroll
      for (int rq = 0; rq < 4; ++rq) {
        const int l = lbase + 8 * rq;
        const int cI = l >> 3;
        const int phys = USWZ16(cI);
        const uint2 uv =
            *(const uint2*)(Us + (w << 13) + (phys << 3) + 4 * qh);
        float uu[4];
        uu[0] = bf2f((ushort)(uv.x & 0xffff));
        uu[1] = bf2f((ushort)(uv.x >> 16));
        uu[2] = bf2f((ushort)(uv.y & 0xffff));
        uu[3] = bf2f((ushort)(uv.y >> 16));
        ushort o[4];
#pragma unroll
        for (int jj = 0; jj < 4; ++jj) {
          const float y = acc[f][rg][rq * 4 + jj] + Dh * uu[jj];
          const float ge = 0.5f * y * (1.0f + erff(y * 0.70710678118654752f));
          o[jj] = f2bf(ge);
        }
        uint2 op;
        op.x = (uint)o[0] | ((uint)o[1] << 16);
        op.y = (uint)o[2] | ((uint)o[3] << 16);
        *(uint2*)(gp + l) = op;
      }
    }
  }
}

// ---------------------------------------------------------------------------
// Kernel 3: transpose g[b][h][l] -> gt[b][l][h] (64x64 tiles, XOR-swizzled)
// ---------------------------------------------------------------------------
__global__ __launch_bounds__(256) void transpose_kernel(
    const ushort* __restrict__ g, ushort* __restrict__ gt) {
  __shared__ __align__(16) ushort Ts[64 * 64];
  const int l0 = blockIdx.x * 64, hh0 = blockIdx.y * 64, b = blockIdx.z;
  const int tid = threadIdx.x;
#pragma unroll
  for (int p = 0; p < 2; ++p) {
    const int hh = (tid >> 3) + 32 * p;
    const int c8 = tid & 7;
    const uint4 v = *(const uint4*)(g + (((size_t)(b * HDIM + hh0 + hh)) << 13)
                                    + l0 + c8 * 8);
    ((uint4*)Ts)[hh * 8 + (c8 ^ ((hh >> 3) & 7))] = v;
  }
  __syncthreads();
#pragma unroll
  for (int p = 0; p < 2; ++p) {
    const int lr = (tid >> 3) + 32 * p;
    const int o8 = tid & 7;
    U16 pk;
#pragma unroll
    for (int j = 0; j < 8; ++j) {
      const int hq = o8 * 8 + j;
      pk.e[j] = Ts[hq * 64 + (((lr >> 3) ^ o8) << 3) + (lr & 7)];
    }
    ((uint4*)(gt + ((size_t)b * LFULL + l0 + lr) * HDIM + hh0))[o8] = pk.u;
  }
}

// ---------------------------------------------------------------------------
// Kernel 4: W fp32 -> bf16
// ---------------------------------------------------------------------------
__global__ __launch_bounds__(256) void wcvt_kernel(const float* __restrict__ W,
                                                   ushort* __restrict__ Wb) {
  const int i = (blockIdx.x * 256 + threadIdx.x) * 8;
  const float4 v0 = *(const float4*)(W + i);
  const float4 v1 = *(const float4*)(W + i + 4);
  U16 pk;
  pk.e[0] = f2bf(v0.x); pk.e[1] = f2bf(v0.y);
  pk.e[2] = f2bf(v0.z); pk.e[3] = f2bf(v0.w);
  pk.e[4] = f2bf(v1.x); pk.e[5] = f2bf(v1.y);
  pk.e[6] = f2bf(v1.z); pk.e[7] = f2bf(v1.w);
  ((uint4*)Wb)[i >> 3] = pk.u;
}

// ---------------------------------------------------------------------------
// Kernel 5: out[b,o,l] = bo[o] + sum_h Wb[o,h]*gt[b,l,h]  (128x128 MFMA GEMM)
// ---------------------------------------------------------------------------
__global__ __launch_bounds__(256, 2) void outmm_kernel(
    const ushort* __restrict__ Wb, const ushort* __restrict__ gt,
    const float* __restrict__ bo, float* __restrict__ out) {
  __shared__ __align__(16) ushort As[128 * 32];
  __shared__ __align__(16) ushort Bs[128 * 32];
  const int tid = threadIdx.x;
  const int l0 = blockIdx.x * 128, o0 = blockIdx.y * 128, b = blockIdx.z;
  const int w = tid >> 6, lane = tid & 63;
  const int wm = w >> 1, wn = w & 1;
  const int col = lane & 15, q = lane >> 4;
  const int srow = lane >> 2, scol = (lane & 3) * 8;
  f32x4 acc[4][4];
#pragma unroll
  for (int m = 0; m < 4; ++m)
#pragma unroll
    for (int n = 0; n < 4; ++n) acc[m][n] = (f32x4){0.f, 0.f, 0.f, 0.f};
  const ushort* gb = gt + ((size_t)b * LFULL) * HDIM;
  for (int kt = 0; kt < 32; ++kt) {
    const int k0 = kt * 32;
    const int r0 = w * 32;
#pragma unroll
    for (int ii = 0; ii < 2; ++ii) {
      const int ra = r0 + ii * 16 + srow;
      gload16(Wb + (size_t)(o0 + ra) * HDIM + k0 + scol,
              As + (r0 + ii * 16) * 32);
      gload16(gb + (size_t)(l0 + ra) * HDIM + k0 + scol,
              Bs + (r0 + ii * 16) * 32);
    }
    __syncthreads();
    bf16x8 aa[4], bb[4];
#pragma unroll
    for (int m = 0; m < 4; ++m) {
      aa[m] = ((const bf16x8*)As)[(wm * 64 + m * 16 + col) * 4 + q];
      bb[m] = ((const bf16x8*)Bs)[(wn * 64 + m * 16 + col) * 4 + q];
    }
#pragma unroll
    for (int m = 0; m < 4; ++m)
#pragma unroll
      for (int n = 0; n < 4; ++n)
        acc[m][n] = __builtin_amdgcn_mfma_f32_16x16x32_bf16(aa[m], bb[n],
                                                            acc[m][n], 0, 0, 0);
    __syncthreads();
  }
#pragma unroll
  for (int m = 0; m < 4; ++m) {
    const int ob = o0 + wm * 64 + m * 16 + q * 4;
    const float4 bv = *(const float4*)(bo + ob);
    const float bva[4] = {bv.x, bv.y, bv.z, bv.w};
#pragma unroll
    for (int n = 0; n < 4; ++n) {
      const int l = l0 + wn * 64 + n * 16 + col;
      float* op = out + (((size_t)(b * HDIM + ob)) << 13) + l;
#pragma unroll
      for (int v = 0; v < 4; ++v) op[(size_t)v << 13] = acc[m][n][v] + bva[v];
    }
  }
}

// ---------------------------------------------------------------------------
extern "C" void kernel_launch(void* const* d_in, const int* in_sizes, int n_in,
                              void* d_out, int out_size, void* d_ws,
                              size_t ws_size, hipStream_t stream) {
  const float* u = (const float*)d_in[0];     // (4, 1024, 8192)
  const float* kern = (const float*)d_in[1];  // (8, 1, 1024, 64)
  const float* D = (const float*)d_in[2];     // (1, 1024)
  const float* W = (const float*)d_in[3];     // (1024, 1024)
  const float* bo = (const float*)d_in[4];    // (1024,)
  float* out = (float*)d_out;                 // (4, 1024, 8192)

  char* ws = (char*)d_ws;
  ushort* g = (ushort*)ws;                                 // [0, 64 MiB)
  ushort* gt = (ushort*)(ws + ((size_t)64 << 20));         // [64, 128 MiB)
  ushort* kbrev = (ushort*)(ws + ((size_t)128 << 20));     // 1024*8448*2 = 16.5 MiB
  ushort* Wb = (ushort*)(ws + ((size_t)128 << 20));        // reuses kbrev region

  k_synth_kernel<<<HDIM, 256, 0, stream>>>(kern, kbrev);
  conv_mfma_kernel<<<HDIM, 256, 0, stream>>>(u, kbrev, D, g);
  // kbrev dead from here; Wb overlays it.
  wcvt_kernel<<<512, 256, 0, stream>>>(W, Wb);
  transpose_kernel<<<dim3(128, 16, 4), 256, 0, stream>>>(g, gt);
  outmm_kernel<<<dim3(64, 8, 4), 256, 0, stream>>>(Wb, gt, bo, out);
}

// Round 9
// 463.969 us; speedup vs baseline: 1.1729x; 1.0181x over previous
//
#include <hip/hip_runtime.h>
#include <hip/hip_bf16.h>

#define LFULL 8192
#define HDIM 1024
#define KPAD 8448  // 66 chunks of 128 elems (last 2 chunks zeros)
#define USTRIDE 8320   // elements per Us row: 128 zero-pad + 8192 data
#define UCHUNKS 1040   // uint4 chunks per Us row (= USTRIDE/8)
#define CSTRIDE 1040   // ring copy stride in bytes (1024 + 16 pad: 4-bank shift)

typedef __attribute__((ext_vector_type(8))) short bf16x8;
typedef __attribute__((ext_vector_type(4))) float f32x4;
typedef __attribute__((ext_vector_type(16))) float f32x16;

union U16 {
  uint4 u;
  bf16x8 s;
  ushort e[8];
};

__device__ __forceinline__ ushort f2bf(float x) {
  union { float f; uint u; } a;
  a.f = x;
  uint r = a.u + 0x7fffu + ((a.u >> 16) & 1u);
  return (ushort)(r >> 16);
}
__device__ __forceinline__ float bf2f(ushort x) {
  union { uint u; float f; } a;
  a.u = ((uint)x) << 16;
  return a.f;
}

__device__ __forceinline__ void gload16(const void* src, void* lds) {
  __builtin_amdgcn_global_load_lds(
      (const __attribute__((address_space(1))) unsigned int*)src,
      (__attribute__((address_space(3))) unsigned int*)lds, 16, 0, 0);
}

__device__ __forceinline__ uint ALIGNB(uint hi, uint lo, uint sh) {
#if __has_builtin(__builtin_amdgcn_alignbyte)
  return __builtin_amdgcn_alignbyte(hi, lo, sh);
#else
  return (uint)((((unsigned long long)hi << 32) | (unsigned long long)lo) >> (8u * sh));
#endif
}

// 4-bit XOR swizzle for Us 16B-chunk index (bijective: low4 ^= bits7:4)
#define USWZ16(cI) ((cI) ^ (((cI) >> 4) & 15))

// ---------------------------------------------------------------------------
// Kernel 1: multi-scale kernel synthesis + L2 norm -> bf16 kbrev[h][8448]
// kbrev[h][x] = k_norm[h][8191-x], zeros for x >= 8192.
// ---------------------------------------------------------------------------
__global__ __launch_bounds__(256) void k_synth_kernel(
    const float* __restrict__ kern, ushort* __restrict__ kout) {
  const int h = blockIdx.x;
  const int tid = threadIdx.x;
  __shared__ float Kw[8][64];
  __shared__ __align__(16) float kv[LFULL];
  __shared__ float red[8];
  for (int idx = tid; idx < 8 * 64; idx += 256) {
    int i = idx >> 6, j = idx & 63;
    Kw[i][j] = kern[(i * HDIM + h) * 64 + j];
  }
  __syncthreads();
  const float mult = (float)(1.0 + 3.0 * (double)h / 1023.0);
  float pw[8];
  pw[7] = 1.0f;
#pragma unroll
  for (int i = 6; i >= 0; --i) pw[i] = pw[i + 1] * mult;
  float ss = 0.0f;
  for (int m = tid; m < LFULL; m += 256) {
    const int i = (m < 64) ? 0 : (32 - __clz(m >> 6));
    const int slog = (i == 0) ? 0 : (i - 1);
    const float inv_s = 1.0f / (float)(1 << slog);
    const int off = (i == 0) ? 0 : (64 << (i - 1));
    const int t = m - off;
    const float pos = ((float)t + 0.5f) * inv_s - 0.5f;
    const float lof = floorf(pos);
    const float wgt = pos - lof;
    int lo = (int)lof;
    int hi = lo + 1;
    lo = min(63, max(0, lo));
    hi = min(63, max(0, hi));
    const float val = (Kw[i][lo] * (1.0f - wgt) + Kw[i][hi] * wgt) * pw[i];
    kv[m] = val;
    ss += val * val;
  }
#pragma unroll
  for (int o = 32; o > 0; o >>= 1) ss += __shfl_xor(ss, o, 64);
  if ((tid & 63) == 0) red[tid >> 6] = ss;
  __syncthreads();
  if (tid == 0) red[0] = sqrtf(red[0] + red[1] + red[2] + red[3]);
  __syncthreads();
  const float inv_norm = 1.0f / red[0];
  ushort* krow = kout + (size_t)h * KPAD;
  for (int m = tid; m < LFULL; m += 256) krow[8191 - m] = f2bf(kv[m] * inv_norm);
  if (tid < 256) krow[8192 + tid] = 0;
}

// ---------------------------------------------------------------------------
// Kernel 2: causal conv via block-Toeplitz 32x32x16 MFMA, T=128 blocks.
// Grid 1024 (1 h). Block: 4 waves (wave = b). acc = 2 F x 4 rg (128 AGPR).
// A-windows from a SHARED 8-phase-copy LDS ring, copy stride 1040 B (4-bank
// shift per copy -> same-offset reads across copies are conflict-free).
// Lane phase s=(c32+1)&7 constant -> window = ONE aligned ds_read_b128.
// Diagonal causal zeros come from a 128-elem zero pad before each Us row
// (jc clamped to -1) -> no mask VALU. 2-step unroll with WA/WB bank swap
// -> no carried-window moves. One lgkmcnt(0)+s_barrier per step.
// ---------------------------------------------------------------------------
__global__ __launch_bounds__(256, 2) void conv_mfma_kernel(
    const float* __restrict__ u, const ushort* __restrict__ kbrev,
    const float* __restrict__ Dp, ushort* __restrict__ g) {
  __shared__ __align__(16) ushort Us[4 * USTRIDE];   // 66.5 KB (pad+data x4)
  __shared__ __align__(16) ushort RingC[8 * 520];    // 8320 B: 8 phase copies
  const int tid = threadIdx.x;
  const int h = blockIdx.x;
  const int w = tid >> 6;  // wave index == b
  const int lane = tid & 63;
  const int c32 = lane & 31;
  const int qh = lane >> 5;
  uint4* Us4 = (uint4*)Us;
  char* ringB = (char*)RingC;
  const int wbase = w * UCHUNKS + 16;  // chunk base of row data (16 pad chunks)

  // ---- zero pads (4 rows x 16 chunks) ----
  if (tid < 64) Us4[(tid >> 4) * UCHUNKS + (tid & 15)] = make_uint4(0, 0, 0, 0);
  // ---- stage u: fp32 -> bf16, XOR16-swizzled 16B chunks (4 rows) ----
  for (int cc = tid; cc < 4096; cc += 256) {
    const int row = cc >> 10, cI = cc & 1023;
    const float* up = u + (((size_t)(row * HDIM + h)) << 13) + (cI << 3);
    const float4 v0 = *(const float4*)up;
    const float4 v1 = *(const float4*)(up + 4);
    U16 pk;
    pk.e[0] = f2bf(v0.x); pk.e[1] = f2bf(v0.y);
    pk.e[2] = f2bf(v0.z); pk.e[3] = f2bf(v0.w);
    pk.e[4] = f2bf(v1.x); pk.e[5] = f2bf(v1.y);
    pk.e[6] = f2bf(v1.z); pk.e[7] = f2bf(v1.w);
    Us4[(row * UCHUNKS + 16) + USWZ16(cI)] = pk.u;
  }

  // ---- ring prologue: preload chunks 62,63,64 into copies 2w, 2w+1 ----
  const ushort* kr = kbrev + (size_t)h * KPAD;
  char* ringE = ringB + (2 * w) * CSTRIDE;
  char* ringO = ringB + (2 * w + 1) * CSTRIDE;
#pragma unroll
  for (int cn = 62; cn <= 64; ++cn) {
    const int x0 = 128 * cn + 2 * lane;
    const uint kEp = *(const uint*)(kr + x0);
    const uint kMp = *(const uint*)(kr + x0 - 2);
    const int off = (2 * x0 + 4 * w) & 1023;
    *(uint*)(ringE + off) = kEp;
    *(uint*)(ringO + off) = ALIGNB(kEp, kMp, 2);
  }
  // prefetch chunk 61 (written at step 0)
  uint kE = *(const uint*)(kr + 61 * 128 + 2 * lane);
  uint kM = *(const uint*)(kr + 61 * 128 + 2 * lane - 2);
  __syncthreads();

  f32x16 acc[2][4];
#pragma unroll
  for (int f = 0; f < 2; ++f)
#pragma unroll
    for (int rg = 0; rg < 4; ++rg)
#pragma unroll
      for (int q = 0; q < 16; ++q) acc[f][rg][q] = 0.0f;

  const int PBASE = 8191 - c32 + 8 * qh;
  const int sph = (c32 + 1) & 7;            // lane's phase copy
  const char* ringR = ringB + sph * CSTRIDE;
  int bd = 2 * (PBASE + sph) + 256;         // off(d,mm) = (bd - 32mm) & 1023

  uint4 WA[8], WB[8];
#pragma unroll
  for (int i = 0; i < 8; ++i) WB[i] = make_uint4(0, 0, 0, 0);

// carried(mm<7) lives in the OTHER bank at [mm+1]; fresh(mm>=7) at [mm-7]
#define FPART(DD, F, WFRESH, WCARR) {                                   \
    const int j0 = (F) * 32 + c32 - (DD);                               \
    const int jc = j0 < 0 ? -1 : j0;                                    \
    const int pb = jc << 4;                                             \
    const int px = jc & 15;                                             \
    _Pragma("unroll")                                                   \
    for (int ks = 0; ks < 8; ++ks) {                                    \
      const int t = 2 * ks + qh;                                        \
      U16 bb;                                                           \
      bb.u = Us4[wbase + pb + (t ^ px)];                                \
      U16 a0, a1, a2, a3;                                               \
      a0.u = (8 - ks >= 7) ? WFRESH[1 - ks] : WCARR[9 - ks];            \
      a1.u = (10 - ks >= 7) ? WFRESH[3 - ks] : WCARR[11 - ks];          \
      a2.u = (12 - ks >= 7) ? WFRESH[5 - ks] : WCARR[13 - ks];          \
      a3.u = WFRESH[7 - ks];                                            \
      acc[F][0] = __builtin_amdgcn_mfma_f32_32x32x16_bf16(a0.s, bb.s, acc[F][0], 0, 0, 0); \
      acc[F][1] = __builtin_amdgcn_mfma_f32_32x32x16_bf16(a1.s, bb.s, acc[F][1], 0, 0, 0); \
      acc[F][2] = __builtin_amdgcn_mfma_f32_32x32x16_bf16(a2.s, bb.s, acc[F][2], 0, 0, 0); \
      acc[F][3] = __builtin_amdgcn_mfma_f32_32x32x16_bf16(a3.s, bb.s, acc[F][3], 0, 0, 0); \
    } }

#define STEP(DD, WFRESH, WCARR, HASF0) {                                \
    const int cw = (61 - (DD)) < 0 ? 0 : (61 - (DD));                   \
    const int offw = (((cw & 3) << 8) + 4 * lane + 4 * w) & 1023;       \
    *(uint*)(ringE + offw) = kE;                                        \
    *(uint*)(ringO + offw) = ALIGNB(kE, kM, 2);                         \
    const int cn = (60 - (DD)) < 0 ? 0 : (60 - (DD));                   \
    const uint kE2 = *(const uint*)(kr + cn * 128 + 2 * lane);          \
    const uint kM2 = *(const uint*)(kr + cn * 128 + 2 * lane - 2);      \
    _Pragma("unroll")                                                   \
    for (int i = 0; i < 8; ++i) {                                       \
      const int off = (bd - 224 - 32 * i) & 1023;                       \
      WFRESH[i] = *(const uint4*)(ringR + off);                         \
    }                                                                   \
    if (HASF0) { FPART(DD, 0, WFRESH, WCARR); FPART(DD, 1, WFRESH, WCARR); } \
    else { FPART(DD, 1, WFRESH, WCARR); }                               \
    kE = kE2; kM = kM2;                                                 \
    bd -= 256;                                                          \
    asm volatile("s_waitcnt lgkmcnt(0)" ::: "memory");                  \
    __builtin_amdgcn_s_barrier();                                       \
    __builtin_amdgcn_sched_barrier(0);                                  \
  }

  for (int dd = 0; dd < 32; dd += 2) {
    STEP(dd, WA, WB, true);
    STEP(dd + 1, WB, WA, true);
  }
  for (int dd = 32; dd < 64; dd += 2) {
    STEP(dd, WA, WB, false);
    STEP(dd + 1, WB, WA, false);
  }

  // ---- epilogue: += D*u, exact GELU, bf16 store ----
  const float Dh = Dp[h];
  ushort* gp = g + (((size_t)(w * HDIM + h)) << 13);
  const ushort* urow = Us + w * USTRIDE + 128;
#pragma unroll
  for (int f = 0; f < 2; ++f) {
#pragma unroll
    for (int rg = 0; rg < 4; ++rg) {
      const int lbase = (f * 32 + c32) * 128 + rg * 32 + 4 * qh;
#pragma unroll
      for (int rq = 0; rq < 4; ++rq) {
        const int l = lbase + 8 * rq;
        const int cI = l >> 3;
        const int phys = USWZ16(cI);
        const uint2 uv = *(const uint2*)(urow + (phys << 3) + 4 * qh);
        float uu[4];
        uu[0] = bf2f((ushort)(uv.x & 0xffff));
        uu[1] = bf2f((ushort)(uv.x >> 16));
        uu[2] = bf2f((ushort)(uv.y & 0xffff));
        uu[3] = bf2f((ushort)(uv.y >> 16));
        ushort o[4];
#pragma unroll
        for (int jj = 0; jj < 4; ++jj) {
          const float y = acc[f][rg][rq * 4 + jj] + Dh * uu[jj];
          const float ge = 0.5f * y * (1.0f + erff(y * 0.70710678118654752f));
          o[jj] = f2bf(ge);
        }
        uint2 op;
        op.x = (uint)o[0] | ((uint)o[1] << 16);
        op.y = (uint)o[2] | ((uint)o[3] << 16);
        *(uint2*)(gp + l) = op;
      }
    }
  }
}

// ---------------------------------------------------------------------------
// Kernel 3: transpose g[b][h][l] -> gt[b][l][h] (64x64 tiles, XOR-swizzled)
// ---------------------------------------------------------------------------
__global__ __launch_bounds__(256) void transpose_kernel(
    const ushort* __restrict__ g, ushort* __restrict__ gt) {
  __shared__ __align__(16) ushort Ts[64 * 64];
  const int l0 = blockIdx.x * 64, hh0 = blockIdx.y * 64, b = blockIdx.z;
  const int tid = threadIdx.x;
#pragma unroll
  for (int p = 0; p < 2; ++p) {
    const int hh = (tid >> 3) + 32 * p;
    const int c8 = tid & 7;
    const uint4 v = *(const uint4*)(g + (((size_t)(b * HDIM + hh0 + hh)) << 13)
                                    + l0 + c8 * 8);
    ((uint4*)Ts)[hh * 8 + (c8 ^ ((hh >> 3) & 7))] = v;
  }
  __syncthreads();
#pragma unroll
  for (int p = 0; p < 2; ++p) {
    const int lr = (tid >> 3) + 32 * p;
    const int o8 = tid & 7;
    U16 pk;
#pragma unroll
    for (int j = 0; j < 8; ++j) {
      const int hq = o8 * 8 + j;
      pk.e[j] = Ts[hq * 64 + (((lr >> 3) ^ o8) << 3) + (lr & 7)];
    }
    ((uint4*)(gt + ((size_t)b * LFULL + l0 + lr) * HDIM + hh0))[o8] = pk.u;
  }
}

// ---------------------------------------------------------------------------
// Kernel 4: W fp32 -> bf16
// ---------------------------------------------------------------------------
__global__ __launch_bounds__(256) void wcvt_kernel(const float* __restrict__ W,
                                                   ushort* __restrict__ Wb) {
  const int i = (blockIdx.x * 256 + threadIdx.x) * 8;
  const float4 v0 = *(const float4*)(W + i);
  const float4 v1 = *(const float4*)(W + i + 4);
  U16 pk;
  pk.e[0] = f2bf(v0.x); pk.e[1] = f2bf(v0.y);
  pk.e[2] = f2bf(v0.z); pk.e[3] = f2bf(v0.w);
  pk.e[4] = f2bf(v1.x); pk.e[5] = f2bf(v1.y);
  pk.e[6] = f2bf(v1.z); pk.e[7] = f2bf(v1.w);
  ((uint4*)Wb)[i >> 3] = pk.u;
}

// ---------------------------------------------------------------------------
// Kernel 5: out[b,o,l] = bo[o] + sum_h Wb[o,h]*gt[b,l,h]  (128x128 MFMA GEMM)
// ---------------------------------------------------------------------------
__global__ __launch_bounds__(256, 2) void outmm_kernel(
    const ushort* __restrict__ Wb, const ushort* __restrict__ gt,
    const float* __restrict__ bo, float* __restrict__ out) {
  __shared__ __align__(16) ushort As[128 * 32];
  __shared__ __align__(16) ushort Bs[128 * 32];
  const int tid = threadIdx.x;
  const int l0 = blockIdx.x * 128, o0 = blockIdx.y * 128, b = blockIdx.z;
  const int w = tid >> 6, lane = tid & 63;
  const int wm = w >> 1, wn = w & 1;
  const int col = lane & 15, q = lane >> 4;
  const int srow = lane >> 2, scol = (lane & 3) * 8;
  f32x4 acc[4][4];
#pragma unroll
  for (int m = 0; m < 4; ++m)
#pragma unroll
    for (int n = 0; n < 4; ++n) acc[m][n] = (f32x4){0.f, 0.f, 0.f, 0.f};
  const ushort* gb = gt + ((size_t)b * LFULL) * HDIM;
  for (int kt = 0; kt < 32; ++kt) {
    const int k0 = kt * 32;
    const int r0 = w * 32;
#pragma unroll
    for (int ii = 0; ii < 2; ++ii) {
      const int ra = r0 + ii * 16 + srow;
      gload16(Wb + (size_t)(o0 + ra) * HDIM + k0 + scol,
              As + (r0 + ii * 16) * 32);
      gload16(gb + (size_t)(l0 + ra) * HDIM + k0 + scol,
              Bs + (r0 + ii * 16) * 32);
    }
    __syncthreads();
    bf16x8 aa[4], bb[4];
#pragma unroll
    for (int m = 0; m < 4; ++m) {
      aa[m] = ((const bf16x8*)As)[(wm * 64 + m * 16 + col) * 4 + q];
      bb[m] = ((const bf16x8*)Bs)[(wn * 64 + m * 16 + col) * 4 + q];
    }
#pragma unroll
    for (int m = 0; m < 4; ++m)
#pragma unroll
      for (int n = 0; n < 4; ++n)
        acc[m][n] = __builtin_amdgcn_mfma_f32_16x16x32_bf16(aa[m], bb[n],
                                                            acc[m][n], 0, 0, 0);
    __syncthreads();
  }
#pragma unroll
  for (int m = 0; m < 4; ++m) {
    const int ob = o0 + wm * 64 + m * 16 + q * 4;
    const float4 bv = *(const float4*)(bo + ob);
    const float bva[4] = {bv.x, bv.y, bv.z, bv.w};
#pragma unroll
    for (int n = 0; n < 4; ++n) {
      const int l = l0 + wn * 64 + n * 16 + col;
      float* op = out + (((size_t)(b * HDIM + ob)) << 13) + l;
#pragma unroll
      for (int v = 0; v < 4; ++v) op[(size_t)v << 13] = acc[m][n][v] + bva[v];
    }
  }
}

// ---------------------------------------------------------------------------
extern "C" void kernel_launch(void* const* d_in, const int* in_sizes, int n_in,
                              void* d_out, int out_size, void* d_ws,
                              size_t ws_size, hipStream_t stream) {
  const float* u = (const float*)d_in[0];     // (4, 1024, 8192)
  const float* kern = (const float*)d_in[1];  // (8, 1, 1024, 64)
  const float* D = (const float*)d_in[2];     // (1, 1024)
  const float* W = (const float*)d_in[3];     // (1024, 1024)
  const float* bo = (const float*)d_in[4];    // (1024,)
  float* out = (float*)d_out;                 // (4, 1024, 8192)

  char* ws = (char*)d_ws;
  ushort* g = (ushort*)ws;                                 // [0, 64 MiB)
  ushort* gt = (ushort*)(ws + ((size_t)64 << 20));         // [64, 128 MiB)
  ushort* kbrev = (ushort*)(ws + ((size_t)128 << 20));     // 1024*8448*2 = 16.5 MiB
  ushort* Wb = (ushort*)(ws + ((size_t)128 << 20));        // reuses kbrev region

  k_synth_kernel<<<HDIM, 256, 0, stream>>>(kern, kbrev);
  conv_mfma_kernel<<<HDIM, 256, 0, stream>>>(u, kbrev, D, g);
  // kbrev dead from here; Wb overlays it.
  wcvt_kernel<<<512, 256, 0, stream>>>(W, Wb);
  transpose_kernel<<<dim3(128, 16, 4), 256, 0, stream>>>(g, gt);
  outmm_kernel<<<dim3(64, 8, 4), 256, 0, stream>>>(Wb, gt, bo, out);
}